// Round 1
// baseline (139.653 us; speedup 1.0000x reference)
//
#include <hip/hip_runtime.h>

#define NB 32
#define SEQ 512
#define DIM 512
#define NH 8
#define DH 64
#define MTOT (NB*SEQ)   // 16384

typedef __attribute__((ext_vector_type(8))) __bf16 bf16x8;   // MFMA operand
typedef __attribute__((ext_vector_type(8))) short s16x8;     // raw bf16 storage
typedef __attribute__((ext_vector_type(4))) float f32x4;
typedef __attribute__((ext_vector_type(16))) float f32x16;
typedef __attribute__((ext_vector_type(4))) unsigned u32x4;

__device__ __forceinline__ float bf2f(short u) {
    union { float f; unsigned u; } x; x.u = ((unsigned)(unsigned short)u) << 16; return x.f;
}
__device__ __forceinline__ short f2bf(float f) {
    union { float f; unsigned u; } x; x.f = f;
    unsigned r = x.u + 0x7FFFu + ((x.u >> 16) & 1u);   // RNE
    return (short)(r >> 16);
}

#define MFMA16(a,b,c) __builtin_amdgcn_mfma_f32_16x16x32_bf16(a,b,c,0,0,0)
#define MFMA32(a,b,c) __builtin_amdgcn_mfma_f32_32x32x16_bf16(a,b,c,0,0,0)

__device__ __forceinline__ void gload_lds16(const void* g, void* l) {
    __builtin_amdgcn_global_load_lds(
        (const __attribute__((address_space(1))) unsigned int*)g,
        (__attribute__((address_space(3))) unsigned int*)l, 16, 0, 0);
}
__device__ __forceinline__ unsigned cvt_pk_bf16(float lo, float hi) {
    unsigned r;
    asm("v_cvt_pk_bf16_f32 %0, %1, %2" : "=v"(r) : "v"(lo), "v"(hi));
    return r;
}

// ---------------------------------------------------------------------------
// Kernel 0: transpose+convert the 4 weight matrices: Wt[z][n][k] = bf16(W[k][n])
// ---------------------------------------------------------------------------
__global__ __launch_bounds__(256) void k_wprep(
    const float* __restrict__ Wq, const float* __restrict__ Wk,
    const float* __restrict__ Wv, const float* __restrict__ Wo,
    short* __restrict__ Wt)
{
    __shared__ float t[64][65];
    const float* W = blockIdx.z==0?Wq: blockIdx.z==1?Wk: blockIdx.z==2?Wv:Wo;
    short* out = Wt + (size_t)blockIdx.z*DIM*DIM;
    int k0 = blockIdx.x*64, n0 = blockIdx.y*64;
    int c = threadIdx.x & 63, r4 = threadIdx.x >> 6;
    #pragma unroll
    for (int i=0;i<16;i++){ int r = i*4 + r4; t[r][c] = W[(size_t)(k0+r)*DIM + n0 + c]; }
    __syncthreads();
    #pragma unroll
    for (int i=0;i<16;i++){ int r = i*4 + r4; out[(size_t)(n0+r)*DIM + k0 + c] = f2bf(t[c][r]); }
}

// ---------------------------------------------------------------------------
// Kernel 1: QKV projections — v3: fully async staging (m97 structure).
// A staged as RAW FP32 via global_load_lds (XOR-swizzled source, rule 21),
// B staged bf16 via global_load_lds (linear; 16x64B subtile reads are
// bank-balanced). bf16 conversion moved to fragment-read time (cvt_pk).
// Zero ds_write, zero staging VALU, loads fly across the MFMA phase.
// ---------------------------------------------------------------------------
__global__ __launch_bounds__(256) void k_projqkv(
    const float* __restrict__ Q, const float* __restrict__ K,
    const short* __restrict__ Wt,
    const float* __restrict__ bq, const float* __restrict__ bk, const float* __restrict__ bv,
    short* __restrict__ qb, short* __restrict__ kb, short* __restrict__ vT)
{
    __shared__ __align__(16) char pool[34816]; // A f32 [0,16384) swz; B bf16 [16384,24576); overlay [128][136] shorts
    short* lds = (short*)pool;
    char* As = pool;
    char* Bs = pool + 16384;
    const int tid = threadIdx.x;
    const int wave = tid >> 6, lane = tid & 63;
    const int z = blockIdx.z;
    const float* A   = (z==0) ? Q : K;
    const short* W   = Wt + z*(DIM*DIM);
    const float* bia = (z==0)?bq:(z==1)?bk:bv;
    const int m0 = blockIdx.x*128, n0 = blockIdx.y*128;

    // Staging sources. A: 4 x 16B chunks/thread; physical chunk P = i*256+tid
    // lands at LDS row P>>3, chunk P&7. Source supplies logical chunk
    // (P&7) ^ (row&7) so the read-side XOR recovers linear K order.
    const float* srcA[4];
    #pragma unroll
    for (int i=0;i<4;i++) {
        int P = i*256 + tid, r = P>>3, pc = P&7, lc = pc ^ (r&7);
        srcA[i] = A + (size_t)(m0+r)*DIM + lc*4;
    }
    // B: 2 x 16B chunks/thread, linear: row P>>2, chunk P&3.
    const short* srcB[2];
    #pragma unroll
    for (int i=0;i<2;i++) {
        int P = i*256 + tid, r = P>>2, c = P&3;
        srcB[i] = W + (size_t)(n0+r)*DIM + c*8;
    }

#define PSTAGE(T) do { \
        const int k0_ = (T)*32; \
        gload_lds16(srcA[0] + k0_, As +         wave*1024); \
        gload_lds16(srcA[1] + k0_, As +  4096 + wave*1024); \
        gload_lds16(srcA[2] + k0_, As +  8192 + wave*1024); \
        gload_lds16(srcA[3] + k0_, As + 12288 + wave*1024); \
        gload_lds16(srcB[0] + k0_, Bs +         wave*1024); \
        gload_lds16(srcB[1] + k0_, Bs +  4096 + wave*1024); \
    } while(0)

    const int wr = (wave>>1)*64, wc = (wave&1)*64;
    const int fr = lane & 15, kg = lane >> 4;

    f32x4 acc[4][4];
    #pragma unroll
    for (int i=0;i<4;i++)
        #pragma unroll
        for (int j=0;j<4;j++) acc[i][j] = (f32x4){0.f,0.f,0.f,0.f};

    PSTAGE(0);

    for (int t=0; t<16; ++t) {
        __syncthreads();                       // vmcnt(0): tile t staged
        float4 alo[4], ahi[4];
        #pragma unroll
        for (int f=0; f<4; ++f) {
            int R = wr + f*16 + fr;
            const char* base = As + R*128;
            alo[f] = *(const float4*)(base + ((((kg<<1)  ) ^ (R&7))<<4));
            ahi[f] = *(const float4*)(base + ((((kg<<1)|1) ^ (R&7))<<4));
        }
        bf16x8 bfr[4];
        #pragma unroll
        for (int f=0; f<4; ++f)
            bfr[f] = *(const bf16x8*)(Bs + (wc + f*16 + fr)*64 + kg*16);
        __syncthreads();                       // lgkmcnt(0): reads in regs, LDS free
        if (t < 15) PSTAGE(t+1);               // async loads fly under the MFMAs
        bf16x8 af[4];
        #pragma unroll
        for (int f=0; f<4; ++f) {
            u32x4 pk = { cvt_pk_bf16(alo[f].x, alo[f].y), cvt_pk_bf16(alo[f].z, alo[f].w),
                         cvt_pk_bf16(ahi[f].x, ahi[f].y), cvt_pk_bf16(ahi[f].z, ahi[f].w) };
            af[f] = __builtin_bit_cast(bf16x8, pk);
        }
        #pragma unroll
        for (int i=0;i<4;i++)
            #pragma unroll
            for (int j=0;j<4;j++) acc[i][j] = MFMA16(af[i], bfr[j], acc[i][j]);
    }
#undef PSTAGE
    __syncthreads();

    // epilogue: acc (+bias) -> overlay [128][136] bf16 -> coalesced store
    const int r0 = (lane>>4)*4;
    #pragma unroll
    for (int i=0;i<4;i++)
        #pragma unroll
        for (int j=0;j<4;j++) {
            int row = wr + i*16 + r0;
            int col = wc + j*16 + fr;
            float bb = bia[n0 + col];
            #pragma unroll
            for (int r=0;r<4;r++) lds[(row+r)*136 + col] = f2bf(acc[i][j][r] + bb);
        }
    __syncthreads();
    if (z < 2) {
        short* out = (z==0)? qb : kb;
        int row = tid>>1, ch = (tid&1)*64;
        #pragma unroll
        for (int j=0;j<8;j++) {
            int col = ch + j*8;
            s16x8 v = *(s16x8*)&lds[row*136 + col];
            *(s16x8*)&out[(size_t)(m0+row)*DIM + n0 + col] = v;
        }
    } else {
        // vT[b][h][d][s] = v[b][s][h*64+d]
        int c = tid>>1, sh = (tid&1)*64;
        int b = m0 >> 9;
        int h = (n0 + c) >> 6, d = (n0 + c) & 63;
        size_t base = ((size_t)(b*NH + h)*DH + d)*SEQ + (m0 & 511) + sh;
        #pragma unroll
        for (int i8=0;i8<8;i8++) {
            s16x8 tv;
            #pragma unroll
            for (int j=0;j<8;j++) tv[j] = lds[(sh + i8*8 + j)*136 + c];
            *(s16x8*)&vT[base + i8*8] = tv;
        }
    }
}

// ---------------------------------------------------------------------------
// Kernel 2: attention per (b,h). 4 waves x 64 q-rows (2 streams/wave),
// 32x32x16 MFMA, swapped QK^T, in-register P, dbuf gload_lds, 1 barrier/tile.
// ---------------------------------------------------------------------------
__global__ __launch_bounds__(256, 2) void k_attn(
    const short* __restrict__ qb, const short* __restrict__ kb,
    const short* __restrict__ vT, short* __restrict__ Oh)
{
    __shared__ short pool[9216];
    __shared__ float invLds[4][2][32];
    char* poolB = (char*)pool;
    const int tid = threadIdx.x, wave = tid>>6, lane = tid&63;
    const int l31 = lane & 31, hi = lane >> 5;
    const int b = blockIdx.z, h = blockIdx.y;
    const int bh = b*NH + h;
    const int bx = blockIdx.x;
    const float SCALE = 0.0441941738241592f;   // 1/sqrt(512)

    bf16x8 qf[2][4];
    #pragma unroll
    for (int u=0; u<2; ++u)
        #pragma unroll
        for (int d=0; d<4; ++d)
            qf[u][d] = *(const bf16x8*)&qb[(size_t)(b*SEQ + bx*256 + u*128 + wave*32 + l31)*DIM + h*DH + d*16 + hi*8];

    const short* gK0 = kb + (size_t)(b*SEQ + l31)*DIM + h*DH + wave*16 + hi*8;
    const short* gV0 = vT + ((size_t)bh*DH + (wave>>1)*32 + l31)*SEQ + (wave&1)*16 + hi*8;

    f32x16 o[2][2];
    #pragma unroll
    for (int u=0;u<2;u++)
        #pragma unroll
        for (int q=0;q<2;q++)
            #pragma unroll
            for (int r=0;r<16;r++) o[u][q][r]=0.f;
    float lsum[2] = {0.f, 0.f};

    gload_lds16(gK0,            poolB + wave*1024);
    gload_lds16(gV0,            poolB + 8192 + wave*1024);

    for (int kt=0; kt<16; ++kt) {
        const int p = kt & 1;
        __syncthreads();
        if (kt < 15) {
            gload_lds16(gK0 + (size_t)(kt+1)*32*DIM, poolB + (p^1)*4096 + wave*1024);
            gload_lds16(gV0 + (kt+1)*32,             poolB + 8192 + (p^1)*4096 + wave*1024);
        }
        const char* Kb = poolB + p*4096 + lane*16;
        bf16x8 kf0 = *(const bf16x8*)(Kb);
        bf16x8 kf1 = *(const bf16x8*)(Kb + 1024);
        bf16x8 kf2 = *(const bf16x8*)(Kb + 2048);
        bf16x8 kf3 = *(const bf16x8*)(Kb + 3072);
        const char* Vb = poolB + 8192 + p*4096 + lane*16;
        bf16x8 v00 = *(const bf16x8*)(Vb);
        bf16x8 v01 = *(const bf16x8*)(Vb + 1024);
        bf16x8 v10 = *(const bf16x8*)(Vb + 2048);
        bf16x8 v11 = *(const bf16x8*)(Vb + 3072);
        #pragma unroll
        for (int u=0; u<2; ++u) {
            f32x16 s;
            #pragma unroll
            for (int r=0;r<16;r++) s[r]=0.f;
            s = MFMA32(kf0, qf[u][0], s);
            s = MFMA32(kf1, qf[u][1], s);
            s = MFMA32(kf2, qf[u][2], s);
            s = MFMA32(kf3, qf[u][3], s);
            float pe[16];
            #pragma unroll
            for (int r=0;r<16;r++) { pe[r] = __expf(s[r]*SCALE - 3.0f); lsum[u] += pe[r]; }
            unsigned pk0 = cvt_pk_bf16(pe[0],  pe[1]);
            unsigned pk1 = cvt_pk_bf16(pe[2],  pe[3]);
            unsigned pk2 = cvt_pk_bf16(pe[4],  pe[5]);
            unsigned pk3 = cvt_pk_bf16(pe[6],  pe[7]);
            unsigned pk4 = cvt_pk_bf16(pe[8],  pe[9]);
            unsigned pk5 = cvt_pk_bf16(pe[10], pe[11]);
            unsigned pk6 = cvt_pk_bf16(pe[12], pe[13]);
            unsigned pk7 = cvt_pk_bf16(pe[14], pe[15]);
            asm("v_permlane32_swap_b32 %0, %1" : "+v"(pk0), "+v"(pk2));
            asm("v_permlane32_swap_b32 %0, %1" : "+v"(pk1), "+v"(pk3));
            asm("v_permlane32_swap_b32 %0, %1" : "+v"(pk4), "+v"(pk6));
            asm("v_permlane32_swap_b32 %0, %1" : "+v"(pk5), "+v"(pk7));
            u32x4 f0w = {pk0, pk1, pk2, pk3};
            u32x4 f1w = {pk4, pk5, pk6, pk7};
            bf16x8 F0 = __builtin_bit_cast(bf16x8, f0w);
            bf16x8 F1 = __builtin_bit_cast(bf16x8, f1w);
            o[u][0] = MFMA32(F0, v00, o[u][0]);
            o[u][0] = MFMA32(F1, v01, o[u][0]);
            o[u][1] = MFMA32(F0, v10, o[u][1]);
            o[u][1] = MFMA32(F1, v11, o[u][1]);
        }
    }
    float linv[2];
    #pragma unroll
    for (int u=0;u<2;u++) { float v = lsum[u]; v += __shfl_xor(v, 32); linv[u] = 1.0f / v; }
    __syncthreads();                           // stage region dead -> overlay
    if (lane < 32) { invLds[wave][0][l31] = linv[0]; invLds[wave][1][l31] = linv[1]; }
    short* O = pool + wave*2304;               // [32][72] per-wave overlay, reused per u
    #pragma unroll
    for (int u=0; u<2; ++u) {
        #pragma unroll
        for (int r=0;r<16;r++) {
            int q = (r&3) + 8*(r>>2) + 4*hi;
            float iq = invLds[wave][u][q];
            O[q*72 + l31]      = f2bf(o[u][0][r] * iq);
            O[q*72 + 32 + l31] = f2bf(o[u][1][r] * iq);
        }
        int rr = lane>>1, c0 = (lane&1)*32;
        size_t baseO = ((size_t)bh*SEQ + bx*256 + u*128 + wave*32 + rr)*DH + c0;
        #pragma unroll
        for (int j=0;j<4;j++) {
            s16x8 v = *(s16x8*)&O[rr*72 + c0 + j*8];
            *(s16x8*)&Oh[baseO + j*8] = v;
        }
    }
}

// ---------------------------------------------------------------------------
// Kernel 3: x0 = LN0(qh + attn)  (residual gather across heads), bf16 out
// ---------------------------------------------------------------------------
__global__ __launch_bounds__(256) void k_ln0(
    const short* __restrict__ qb, const short* __restrict__ Oh,
    const float* __restrict__ g, const float* __restrict__ bt,
    short* __restrict__ x0)
{
    int wave = threadIdx.x>>6, lane = threadIdx.x&63;
    int row = blockIdx.x*4 + wave;
    int b = row >> 9, s = row & 511;
    int f0 = lane*8;
    s16x8 qv = *(const s16x8*)&qb[(size_t)row*DIM + f0];
    int h = f0 >> 6, d = f0 & 63;
    s16x8 ov = *(const s16x8*)&Oh[((size_t)(b*NH+h)*SEQ + s)*DH + d];
    float x[8];
    float sm=0.f, sq=0.f;
    #pragma unroll
    for (int j=0;j<8;j++) { x[j] = bf2f(qv[j]) + bf2f(ov[j]); sm += x[j]; sq += x[j]*x[j]; }
    #pragma unroll
    for (int off=1; off<64; off<<=1) { sm += __shfl_xor(sm,off); sq += __shfl_xor(sq,off); }
    float mean = sm*(1.0f/512.0f);
    float var  = sq*(1.0f/512.0f) - mean*mean;
    float inv  = rsqrtf(var + 1e-5f);
    float4 g0 = *(const float4*)&g[f0],  g1 = *(const float4*)&g[f0+4];
    float4 t0 = *(const float4*)&bt[f0], t1 = *(const float4*)&bt[f0+4];
    s16x8 outv;
    outv[0]=f2bf((x[0]-mean)*inv*g0.x + t0.x); outv[1]=f2bf((x[1]-mean)*inv*g0.y + t0.y);
    outv[2]=f2bf((x[2]-mean)*inv*g0.z + t0.z); outv[3]=f2bf((x[3]-mean)*inv*g0.w + t0.w);
    outv[4]=f2bf((x[4]-mean)*inv*g1.x + t1.x); outv[5]=f2bf((x[5]-mean)*inv*g1.y + t1.y);
    outv[6]=f2bf((x[6]-mean)*inv*g1.z + t1.z); outv[7]=f2bf((x[7]-mean)*inv*g1.w + t1.w);
    *(s16x8*)&x0[(size_t)row*DIM + f0] = outv;
}

// ---------------------------------------------------------------------------
// Kernel 4 (FUSED): out = LN1( x0 + relu(x0 @ Wo + bo) ), f32 out.
// 64x512 tile (FULL output width) so LN1 can run in the epilogue.
// 8 waves = 4 row-groups x 2 col-halves; per-wave acc[16] (r10-gemmy shape).
// gload_lds double-buffered staging (A 4KB + B 32KB per buf), XOR-swizzled src.
// ---------------------------------------------------------------------------
__global__ __launch_bounds__(512) void k_gemmy_ln(
    const short* __restrict__ x0, const short* __restrict__ Wto,
    const float* __restrict__ bo,
    const float* __restrict__ g, const float* __restrict__ bt,
    float* __restrict__ out)
{
    __shared__ __align__(16) char pool[73728];  // A dbuf 2x4KB @0; B dbuf 2x32KB @8192; overlay [64][520] shorts
    const int tid = threadIdx.x;
    const int wave = tid >> 6, lane = tid & 63;
    const int fr = lane & 15, g4 = lane >> 4;

    int L = ((int)blockIdx.x & 7)*32 + ((int)blockIdx.x >> 3);   // 256 blocks, XCD-chunked
    const int m0 = L*64;

    // staging sources (rule 21: linear LDS dest + inverse-swizzled global src)
    size_t srcA = 0;
    if (wave < 4) {
        int r = tid>>2, c = tid&3;                               // A: 64 rows x 4 chunks(16B)
        srcA = (size_t)(m0 + r)*DIM + ((c ^ ((r>>1)&3))<<3);
    }
    size_t srcB[4];
    #pragma unroll
    for (int i=0;i<4;i++) {
        int s = i*512 + tid, r = s>>2, c = s&3;                  // B: 512 rows x 4 chunks(16B)
        srcB[i] = (size_t)r*DIM + ((c ^ ((r>>1)&3))<<3);
    }

    f32x4 acc[16];
    #pragma unroll
    for (int j=0;j<16;j++) acc[j] = (f32x4){0.f,0.f,0.f,0.f};

#define GSTAGE(T, BUF) do { \
        const short* As_ = x0  + (T)*32; \
        const short* Bs_ = Wto + (T)*32; \
        if (wave < 4) gload_lds16(As_ + srcA, pool + (BUF)*4096 + wave*1024); \
        char* dB_ = pool + 8192 + (BUF)*32768; \
        gload_lds16(Bs_ + srcB[0], dB_ +     0 + wave*1024); \
        gload_lds16(Bs_ + srcB[1], dB_ +  8192 + wave*1024); \
        gload_lds16(Bs_ + srcB[2], dB_ + 16384 + wave*1024); \
        gload_lds16(Bs_ + srcB[3], dB_ + 24576 + wave*1024); \
    } while(0)

    GSTAGE(0, 0);
    __syncthreads();

    int cur = 0;
    for (int t=0; t<16; ++t) {
        if (t < 15) GSTAGE(t+1, cur^1);
        const char* pA = pool + cur*4096;
        const char* pB = pool + 8192 + cur*32768;
        int R = (wave>>1)*16 + fr;
        bf16x8 af = *(const bf16x8*)(pA + R*64 + ((g4 ^ ((R>>1)&3))<<4));
        #pragma unroll
        for (int j=0;j<16;j++) {
            int Rb = (wave&1)*256 + j*16 + fr;
            bf16x8 bf = *(const bf16x8*)(pB + Rb*64 + ((g4 ^ ((Rb>>1)&3))<<4));
            acc[j] = MFMA16(af, bf, acc[j]);
        }
        __syncthreads();
        cur ^= 1;
    }
#undef GSTAGE

    // epilogue 1: relu(acc+bias) -> overlay [64][520] bf16
    short (*Lo)[520] = (short(*)[520])pool;
    {
        int wrow = (wave>>1)*16 + g4*4;
        int cbase = (wave&1)*256;
        #pragma unroll
        for (int j=0;j<16;j++) {
            int col = cbase + j*16 + fr;
            float bb = bo[col];
            #pragma unroll
            for (int r=0;r<4;r++) {
                float vv = acc[j][r] + bb;
                vv = vv > 0.f ? vv : 0.f;
                Lo[wrow + r][col] = f2bf(vv);
            }
        }
    }
    __syncthreads();

    // epilogue 2: per row: x = x0 + relu(...); LN1; write f32 out.
    // 8 waves x 8 rows each; lane covers 8 cols.
    int f0 = lane*8;
    float4 gg0 = *(const float4*)&g[f0],  gg1 = *(const float4*)&g[f0+4];
    float4 tt0 = *(const float4*)&bt[f0], tt1 = *(const float4*)&bt[f0+4];
    #pragma unroll
    for (int rr=0; rr<8; ++rr) {
        int row = wave*8 + rr;
        s16x8 rv = *(s16x8*)&Lo[row][f0];
        s16x8 xv = *(const s16x8*)&x0[(size_t)(m0+row)*DIM + f0];
        float x[8];
        float sm=0.f, sq=0.f;
        #pragma unroll
        for (int j=0;j<8;j++) { x[j] = bf2f(rv[j]) + bf2f(xv[j]); sm += x[j]; sq += x[j]*x[j]; }
        #pragma unroll
        for (int off=1; off<64; off<<=1) { sm += __shfl_xor(sm,off); sq += __shfl_xor(sq,off); }
        float mean = sm*(1.0f/512.0f);
        float var  = sq*(1.0f/512.0f) - mean*mean;
        float inv  = rsqrtf(var + 1e-5f);
        float4 o0, o1;
        o0.x=(x[0]-mean)*inv*gg0.x + tt0.x; o0.y=(x[1]-mean)*inv*gg0.y + tt0.y;
        o0.z=(x[2]-mean)*inv*gg0.z + tt0.z; o0.w=(x[3]-mean)*inv*gg0.w + tt0.w;
        o1.x=(x[4]-mean)*inv*gg1.x + tt1.x; o1.y=(x[5]-mean)*inv*gg1.y + tt1.y;
        o1.z=(x[6]-mean)*inv*gg1.z + tt1.z; o1.w=(x[7]-mean)*inv*gg1.w + tt1.w;
        *(float4*)&out[(size_t)(m0+row)*DIM + f0]     = o0;
        *(float4*)&out[(size_t)(m0+row)*DIM + f0 + 4] = o1;
    }
}

// ---------------------------------------------------------------------------
extern "C" void kernel_launch(void* const* d_in, const int* in_sizes, int n_in,
                              void* d_out, int out_size, void* d_ws, size_t ws_size,
                              hipStream_t stream)
{
    const float* Q  = (const float*)d_in[0];
    const float* K  = (const float*)d_in[1];
    const float* Wq = (const float*)d_in[2];
    const float* bq = (const float*)d_in[3];
    const float* Wk = (const float*)d_in[4];
    const float* bk = (const float*)d_in[5];
    const float* Wv = (const float*)d_in[6];
    const float* bv = (const float*)d_in[7];
    const float* Wo = (const float*)d_in[8];
    const float* bo = (const float*)d_in[9];
    const float* g0 = (const float*)d_in[10];
    const float* be0= (const float*)d_in[11];
    const float* g1 = (const float*)d_in[12];
    const float* be1= (const float*)d_in[13];
    float* out = (float*)d_out;

    char* ws = (char*)d_ws;
    size_t off = 0;
    short* Wt = (short*)(ws + off); off += (size_t)4*DIM*DIM*2;      //  2.10 MB
    short* qb = (short*)(ws + off); off += (size_t)MTOT*DIM*2;       // 16.78 MB
    short* kb = (short*)(ws + off); off += (size_t)MTOT*DIM*2;
    short* vT = (short*)(ws + off); off += (size_t)MTOT*DIM*2;
    short* Oh = (short*)(ws + off); off += (size_t)MTOT*DIM*2;       // total ~69.2 MB
    short* x0 = vT;   // vT dead after k_attn

    k_wprep   <<<dim3(8,8,4),   256, 0, stream>>>(Wq,Wk,Wv,Wo,Wt);
    k_projqkv <<<dim3(128,4,3), 256, 0, stream>>>(Q,K,Wt,bq,bk,bv,qb,kb,vT);
    k_attn    <<<dim3(2,NH,NB), 256, 0, stream>>>(qb,kb,vT,Oh);
    k_ln0     <<<dim3(MTOT/4),  256, 0, stream>>>(qb,Oh,g0,be0,x0);
    k_gemmy_ln<<<dim3(256),     512, 0, stream>>>(x0, Wt + (size_t)3*DIM*DIM, bo, g1, be1, out);
}

// Round 2
// 135.079 us; speedup vs baseline: 1.0339x; 1.0339x over previous
//
#include <hip/hip_runtime.h>

#define NB 32
#define SEQ 512
#define DIM 512
#define NH 8
#define DH 64
#define MTOT (NB*SEQ)   // 16384

typedef __attribute__((ext_vector_type(8))) __bf16 bf16x8;   // MFMA operand
typedef __attribute__((ext_vector_type(8))) short s16x8;     // raw bf16 storage
typedef __attribute__((ext_vector_type(4))) float f32x4;
typedef __attribute__((ext_vector_type(16))) float f32x16;
typedef __attribute__((ext_vector_type(4))) unsigned u32x4;

__device__ __forceinline__ float bf2f(short u) {
    union { float f; unsigned u; } x; x.u = ((unsigned)(unsigned short)u) << 16; return x.f;
}
__device__ __forceinline__ short f2bf(float f) {
    union { float f; unsigned u; } x; x.f = f;
    unsigned r = x.u + 0x7FFFu + ((x.u >> 16) & 1u);   // RNE
    return (short)(r >> 16);
}

#define MFMA16(a,b,c) __builtin_amdgcn_mfma_f32_16x16x32_bf16(a,b,c,0,0,0)
#define MFMA32(a,b,c) __builtin_amdgcn_mfma_f32_32x32x16_bf16(a,b,c,0,0,0)

__device__ __forceinline__ void gload_lds16(const void* g, void* l) {
    __builtin_amdgcn_global_load_lds(
        (const __attribute__((address_space(1))) unsigned int*)g,
        (__attribute__((address_space(3))) unsigned int*)l, 16, 0, 0);
}
__device__ __forceinline__ unsigned cvt_pk_bf16(float lo, float hi) {
    unsigned r;
    asm("v_cvt_pk_bf16_f32 %0, %1, %2" : "=v"(r) : "v"(lo), "v"(hi));
    return r;
}

// ---------------------------------------------------------------------------
// Kernel 0: transpose+convert the 4 weight matrices: Wt[z][n][k] = bf16(W[k][n])
// ---------------------------------------------------------------------------
__global__ __launch_bounds__(256) void k_wprep(
    const float* __restrict__ Wq, const float* __restrict__ Wk,
    const float* __restrict__ Wv, const float* __restrict__ Wo,
    short* __restrict__ Wt)
{
    __shared__ float t[64][65];
    const float* W = blockIdx.z==0?Wq: blockIdx.z==1?Wk: blockIdx.z==2?Wv:Wo;
    short* out = Wt + (size_t)blockIdx.z*DIM*DIM;
    int k0 = blockIdx.x*64, n0 = blockIdx.y*64;
    int c = threadIdx.x & 63, r4 = threadIdx.x >> 6;
    #pragma unroll
    for (int i=0;i<16;i++){ int r = i*4 + r4; t[r][c] = W[(size_t)(k0+r)*DIM + n0 + c]; }
    __syncthreads();
    #pragma unroll
    for (int i=0;i<16;i++){ int r = i*4 + r4; out[(size_t)(n0+r)*DIM + k0 + c] = f2bf(t[c][r]); }
}

// ---------------------------------------------------------------------------
// Kernel 1: QKV projections — v4: depth-2 counted-vmcnt pipeline (T4) +
// B-operand XOR swizzle (T2). Double-buffered A (fp32, 2x16KB) and B (bf16,
// 2x8KB). Raw s_barrier via asm (memory-fence both sides), waits:
//   top of iter t: vmcnt(6) [t<15] / vmcnt(0) [t==15]  -> tile t landed
//   after frag reads: lgkmcnt(0) + barrier              -> safe to overwrite
// 12 loads in flight steady-state; each tile's loads get a full iteration of
// latency cover instead of ~80 cycles.
// ---------------------------------------------------------------------------
__global__ __launch_bounds__(256) void k_projqkv(
    const float* __restrict__ Q, const float* __restrict__ K,
    const short* __restrict__ Wt,
    const float* __restrict__ bq, const float* __restrict__ bk, const float* __restrict__ bv,
    short* __restrict__ qb, short* __restrict__ kb, short* __restrict__ vT)
{
    __shared__ __align__(16) char pool[49152]; // A dbuf 2x16KB @0; B dbuf 2x8KB @32768; overlay [128][136] shorts
    short* lds = (short*)pool;
    const int tid = threadIdx.x;
    const int wave = tid >> 6, lane = tid & 63;
    const int z = blockIdx.z;
    const float* A   = (z==0) ? Q : K;
    const short* W   = Wt + z*(DIM*DIM);
    const float* bia = (z==0)?bq:(z==1)?bk:bv;
    const int m0 = blockIdx.x*128, n0 = blockIdx.y*128;

    // A: 4 x 16B chunks/thread; physical chunk P = i*256+tid lands at LDS row
    // P>>3, chunk P&7. Source supplies logical chunk (P&7)^(row&7) so the
    // read-side XOR recovers linear K order. (128B rows are bank-aligned;
    // chunk^row spread gives 2-way = free.)
    const float* srcA[4];
    #pragma unroll
    for (int i=0;i<4;i++) {
        int P = i*256 + tid, r = P>>3, pc = P&7, lc = pc ^ (r&7);
        srcA[i] = A + (size_t)(m0+r)*DIM + lc*4;
    }
    // B: 2 x 16B chunks/thread; physical chunk P = i*256+tid at row P>>2,
    // chunk P&3. Source supplies chunk (P&3)^((r>>1)&3): read of 16
    // consecutive rows at fixed chunk then spreads (parity,chunk) bijectively
    // over row&7 -> 2-way aliasing (was 8-way).
    const short* srcB[2];
    #pragma unroll
    for (int i=0;i<2;i++) {
        int P = i*256 + tid, r = P>>2, c = P&3;
        srcB[i] = W + (size_t)(n0+r)*DIM + ((c ^ ((r>>1)&3))<<3);
    }

#define PSTAGE(T, BUF) do { \
        const int k0_ = (T)*32; \
        char* dA_ = pool + (BUF)*16384; \
        char* dB_ = pool + 32768 + (BUF)*8192; \
        gload_lds16(srcA[0] + k0_, dA_ +         wave*1024); \
        gload_lds16(srcA[1] + k0_, dA_ +  4096 + wave*1024); \
        gload_lds16(srcA[2] + k0_, dA_ +  8192 + wave*1024); \
        gload_lds16(srcA[3] + k0_, dA_ + 12288 + wave*1024); \
        gload_lds16(srcB[0] + k0_, dB_ +         wave*1024); \
        gload_lds16(srcB[1] + k0_, dB_ +  4096 + wave*1024); \
    } while(0)

    const int wr = (wave>>1)*64, wc = (wave&1)*64;
    const int fr = lane & 15, kg = lane >> 4;

    f32x4 acc[4][4];
    #pragma unroll
    for (int i=0;i<4;i++)
        #pragma unroll
        for (int j=0;j<4;j++) acc[i][j] = (f32x4){0.f,0.f,0.f,0.f};

    PSTAGE(0, 0);
    PSTAGE(1, 1);

    for (int t=0; t<16; ++t) {
        const int cur = t & 1;
        // tile t's 6 loads are the oldest; in-order vmcnt retire means
        // vmcnt(6) guarantees they've landed (P(t+1)'s 6 may still fly).
        if (t < 15) asm volatile("s_waitcnt vmcnt(6)" ::: "memory");
        else        asm volatile("s_waitcnt vmcnt(0)" ::: "memory");
        asm volatile("s_barrier" ::: "memory");        // all waves' tile-t loads landed

        const char* pA = pool + cur*16384;
        const char* pB = pool + 32768 + cur*8192;
        float4 alo[4], ahi[4];
        #pragma unroll
        for (int f=0; f<4; ++f) {
            int R = wr + f*16 + fr;
            const char* base = pA + R*128;
            alo[f] = *(const float4*)(base + ((((kg<<1)  ) ^ (R&7))<<4));
            ahi[f] = *(const float4*)(base + ((((kg<<1)|1) ^ (R&7))<<4));
        }
        bf16x8 bfr[4];
        #pragma unroll
        for (int f=0; f<4; ++f) {
            int Rb = wc + f*16 + fr;
            bfr[f] = *(const bf16x8*)(pB + Rb*64 + ((kg ^ ((Rb>>1)&3))<<4));
        }
        asm volatile("s_waitcnt lgkmcnt(0)" ::: "memory");  // my reads complete
        asm volatile("s_barrier" ::: "memory");             // everyone's reads complete
        if (t < 14) PSTAGE(t+2, cur);          // overwrite the buffer just consumed

        bf16x8 af[4];
        #pragma unroll
        for (int f=0; f<4; ++f) {
            u32x4 pk = { cvt_pk_bf16(alo[f].x, alo[f].y), cvt_pk_bf16(alo[f].z, alo[f].w),
                         cvt_pk_bf16(ahi[f].x, ahi[f].y), cvt_pk_bf16(ahi[f].z, ahi[f].w) };
            af[f] = __builtin_bit_cast(bf16x8, pk);
        }
        #pragma unroll
        for (int i=0;i<4;i++)
            #pragma unroll
            for (int j=0;j<4;j++) acc[i][j] = MFMA16(af[i], bfr[j], acc[i][j]);
    }
#undef PSTAGE
    __syncthreads();

    // epilogue: acc (+bias) -> overlay [128][136] bf16 -> coalesced store
    const int r0 = (lane>>4)*4;
    #pragma unroll
    for (int i=0;i<4;i++)
        #pragma unroll
        for (int j=0;j<4;j++) {
            int row = wr + i*16 + r0;
            int col = wc + j*16 + fr;
            float bb = bia[n0 + col];
            #pragma unroll
            for (int r=0;r<4;r++) lds[(row+r)*136 + col] = f2bf(acc[i][j][r] + bb);
        }
    __syncthreads();
    if (z < 2) {
        short* out = (z==0)? qb : kb;
        int row = tid>>1, ch = (tid&1)*64;
        #pragma unroll
        for (int j=0;j<8;j++) {
            int col = ch + j*8;
            s16x8 v = *(s16x8*)&lds[row*136 + col];
            *(s16x8*)&out[(size_t)(m0+row)*DIM + n0 + col] = v;
        }
    } else {
        // vT[b][h][d][s] = v[b][s][h*64+d]
        int c = tid>>1, sh = (tid&1)*64;
        int b = m0 >> 9;
        int h = (n0 + c) >> 6, d = (n0 + c) & 63;
        size_t base = ((size_t)(b*NH + h)*DH + d)*SEQ + (m0 & 511) + sh;
        #pragma unroll
        for (int i8=0;i8<8;i8++) {
            s16x8 tv;
            #pragma unroll
            for (int j=0;j<8;j++) tv[j] = lds[(sh + i8*8 + j)*136 + c];
            *(s16x8*)&vT[base + i8*8] = tv;
        }
    }
}

// ---------------------------------------------------------------------------
// Kernel 2: attention per (b,h). 4 waves x 64 q-rows (2 streams/wave),
// 32x32x16 MFMA, swapped QK^T, in-register P, dbuf gload_lds, 1 barrier/tile.
// ---------------------------------------------------------------------------
__global__ __launch_bounds__(256, 2) void k_attn(
    const short* __restrict__ qb, const short* __restrict__ kb,
    const short* __restrict__ vT, short* __restrict__ Oh)
{
    __shared__ short pool[9216];
    __shared__ float invLds[4][2][32];
    char* poolB = (char*)pool;
    const int tid = threadIdx.x, wave = tid>>6, lane = tid&63;
    const int l31 = lane & 31, hi = lane >> 5;
    const int b = blockIdx.z, h = blockIdx.y;
    const int bh = b*NH + h;
    const int bx = blockIdx.x;
    const float SCALE = 0.0441941738241592f;   // 1/sqrt(512)

    bf16x8 qf[2][4];
    #pragma unroll
    for (int u=0; u<2; ++u)
        #pragma unroll
        for (int d=0; d<4; ++d)
            qf[u][d] = *(const bf16x8*)&qb[(size_t)(b*SEQ + bx*256 + u*128 + wave*32 + l31)*DIM + h*DH + d*16 + hi*8];

    const short* gK0 = kb + (size_t)(b*SEQ + l31)*DIM + h*DH + wave*16 + hi*8;
    const short* gV0 = vT + ((size_t)bh*DH + (wave>>1)*32 + l31)*SEQ + (wave&1)*16 + hi*8;

    f32x16 o[2][2];
    #pragma unroll
    for (int u=0;u<2;u++)
        #pragma unroll
        for (int q=0;q<2;q++)
            #pragma unroll
            for (int r=0;r<16;r++) o[u][q][r]=0.f;
    float lsum[2] = {0.f, 0.f};

    gload_lds16(gK0,            poolB + wave*1024);
    gload_lds16(gV0,            poolB + 8192 + wave*1024);

    for (int kt=0; kt<16; ++kt) {
        const int p = kt & 1;
        __syncthreads();
        if (kt < 15) {
            gload_lds16(gK0 + (size_t)(kt+1)*32*DIM, poolB + (p^1)*4096 + wave*1024);
            gload_lds16(gV0 + (kt+1)*32,             poolB + 8192 + (p^1)*4096 + wave*1024);
        }
        const char* Kb = poolB + p*4096 + lane*16;
        bf16x8 kf0 = *(const bf16x8*)(Kb);
        bf16x8 kf1 = *(const bf16x8*)(Kb + 1024);
        bf16x8 kf2 = *(const bf16x8*)(Kb + 2048);
        bf16x8 kf3 = *(const bf16x8*)(Kb + 3072);
        const char* Vb = poolB + 8192 + p*4096 + lane*16;
        bf16x8 v00 = *(const bf16x8*)(Vb);
        bf16x8 v01 = *(const bf16x8*)(Vb + 1024);
        bf16x8 v10 = *(const bf16x8*)(Vb + 2048);
        bf16x8 v11 = *(const bf16x8*)(Vb + 3072);
        #pragma unroll
        for (int u=0; u<2; ++u) {
            f32x16 s;
            #pragma unroll
            for (int r=0;r<16;r++) s[r]=0.f;
            s = MFMA32(kf0, qf[u][0], s);
            s = MFMA32(kf1, qf[u][1], s);
            s = MFMA32(kf2, qf[u][2], s);
            s = MFMA32(kf3, qf[u][3], s);
            float pe[16];
            #pragma unroll
            for (int r=0;r<16;r++) { pe[r] = __expf(s[r]*SCALE - 3.0f); lsum[u] += pe[r]; }
            unsigned pk0 = cvt_pk_bf16(pe[0],  pe[1]);
            unsigned pk1 = cvt_pk_bf16(pe[2],  pe[3]);
            unsigned pk2 = cvt_pk_bf16(pe[4],  pe[5]);
            unsigned pk3 = cvt_pk_bf16(pe[6],  pe[7]);
            unsigned pk4 = cvt_pk_bf16(pe[8],  pe[9]);
            unsigned pk5 = cvt_pk_bf16(pe[10], pe[11]);
            unsigned pk6 = cvt_pk_bf16(pe[12], pe[13]);
            unsigned pk7 = cvt_pk_bf16(pe[14], pe[15]);
            asm("v_permlane32_swap_b32 %0, %1" : "+v"(pk0), "+v"(pk2));
            asm("v_permlane32_swap_b32 %0, %1" : "+v"(pk1), "+v"(pk3));
            asm("v_permlane32_swap_b32 %0, %1" : "+v"(pk4), "+v"(pk6));
            asm("v_permlane32_swap_b32 %0, %1" : "+v"(pk5), "+v"(pk7));
            u32x4 f0w = {pk0, pk1, pk2, pk3};
            u32x4 f1w = {pk4, pk5, pk6, pk7};
            bf16x8 F0 = __builtin_bit_cast(bf16x8, f0w);
            bf16x8 F1 = __builtin_bit_cast(bf16x8, f1w);
            o[u][0] = MFMA32(F0, v00, o[u][0]);
            o[u][0] = MFMA32(F1, v01, o[u][0]);
            o[u][1] = MFMA32(F0, v10, o[u][1]);
            o[u][1] = MFMA32(F1, v11, o[u][1]);
        }
    }
    float linv[2];
    #pragma unroll
    for (int u=0;u<2;u++) { float v = lsum[u]; v += __shfl_xor(v, 32); linv[u] = 1.0f / v; }
    __syncthreads();                           // stage region dead -> overlay
    if (lane < 32) { invLds[wave][0][l31] = linv[0]; invLds[wave][1][l31] = linv[1]; }
    short* O = pool + wave*2304;               // [32][72] per-wave overlay, reused per u
    #pragma unroll
    for (int u=0; u<2; ++u) {
        #pragma unroll
        for (int r=0;r<16;r++) {
            int q = (r&3) + 8*(r>>2) + 4*hi;
            float iq = invLds[wave][u][q];
            O[q*72 + l31]      = f2bf(o[u][0][r] * iq);
            O[q*72 + 32 + l31] = f2bf(o[u][1][r] * iq);
        }
        int rr = lane>>1, c0 = (lane&1)*32;
        size_t baseO = ((size_t)bh*SEQ + bx*256 + u*128 + wave*32 + rr)*DH + c0;
        #pragma unroll
        for (int j=0;j<4;j++) {
            s16x8 v = *(s16x8*)&O[rr*72 + c0 + j*8];
            *(s16x8*)&Oh[baseO + j*8] = v;
        }
    }
}

// ---------------------------------------------------------------------------
// Kernel 3: x0 = LN0(qh + attn)  (residual gather across heads), bf16 out
// ---------------------------------------------------------------------------
__global__ __launch_bounds__(256) void k_ln0(
    const short* __restrict__ qb, const short* __restrict__ Oh,
    const float* __restrict__ g, const float* __restrict__ bt,
    short* __restrict__ x0)
{
    int wave = threadIdx.x>>6, lane = threadIdx.x&63;
    int row = blockIdx.x*4 + wave;
    int b = row >> 9, s = row & 511;
    int f0 = lane*8;
    s16x8 qv = *(const s16x8*)&qb[(size_t)row*DIM + f0];
    int h = f0 >> 6, d = f0 & 63;
    s16x8 ov = *(const s16x8*)&Oh[((size_t)(b*NH+h)*SEQ + s)*DH + d];
    float x[8];
    float sm=0.f, sq=0.f;
    #pragma unroll
    for (int j=0;j<8;j++) { x[j] = bf2f(qv[j]) + bf2f(ov[j]); sm += x[j]; sq += x[j]*x[j]; }
    #pragma unroll
    for (int off=1; off<64; off<<=1) { sm += __shfl_xor(sm,off); sq += __shfl_xor(sq,off); }
    float mean = sm*(1.0f/512.0f);
    float var  = sq*(1.0f/512.0f) - mean*mean;
    float inv  = rsqrtf(var + 1e-5f);
    float4 g0 = *(const float4*)&g[f0],  g1 = *(const float4*)&g[f0+4];
    float4 t0 = *(const float4*)&bt[f0], t1 = *(const float4*)&bt[f0+4];
    s16x8 outv;
    outv[0]=f2bf((x[0]-mean)*inv*g0.x + t0.x); outv[1]=f2bf((x[1]-mean)*inv*g0.y + t0.y);
    outv[2]=f2bf((x[2]-mean)*inv*g0.z + t0.z); outv[3]=f2bf((x[3]-mean)*inv*g0.w + t0.w);
    outv[4]=f2bf((x[4]-mean)*inv*g1.x + t1.x); outv[5]=f2bf((x[5]-mean)*inv*g1.y + t1.y);
    outv[6]=f2bf((x[6]-mean)*inv*g1.z + t1.z); outv[7]=f2bf((x[7]-mean)*inv*g1.w + t1.w);
    *(s16x8*)&x0[(size_t)row*DIM + f0] = outv;
}

// ---------------------------------------------------------------------------
// Kernel 4 (FUSED): out = LN1( x0 + relu(x0 @ Wo + bo) ), f32 out.
// 64x512 tile (FULL output width) so LN1 can run in the epilogue.
// 8 waves = 4 row-groups x 2 col-halves; per-wave acc[16] (r10-gemmy shape).
// gload_lds double-buffered staging (A 4KB + B 32KB per buf), XOR-swizzled src.
// ---------------------------------------------------------------------------
__global__ __launch_bounds__(512) void k_gemmy_ln(
    const short* __restrict__ x0, const short* __restrict__ Wto,
    const float* __restrict__ bo,
    const float* __restrict__ g, const float* __restrict__ bt,
    float* __restrict__ out)
{
    __shared__ __align__(16) char pool[73728];  // A dbuf 2x4KB @0; B dbuf 2x32KB @8192; overlay [64][520] shorts
    const int tid = threadIdx.x;
    const int wave = tid >> 6, lane = tid & 63;
    const int fr = lane & 15, g4 = lane >> 4;

    int L = ((int)blockIdx.x & 7)*32 + ((int)blockIdx.x >> 3);   // 256 blocks, XCD-chunked
    const int m0 = L*64;

    // staging sources (rule 21: linear LDS dest + inverse-swizzled global src)
    size_t srcA = 0;
    if (wave < 4) {
        int r = tid>>2, c = tid&3;                               // A: 64 rows x 4 chunks(16B)
        srcA = (size_t)(m0 + r)*DIM + ((c ^ ((r>>1)&3))<<3);
    }
    size_t srcB[4];
    #pragma unroll
    for (int i=0;i<4;i++) {
        int s = i*512 + tid, r = s>>2, c = s&3;                  // B: 512 rows x 4 chunks(16B)
        srcB[i] = (size_t)r*DIM + ((c ^ ((r>>1)&3))<<3);
    }

    f32x4 acc[16];
    #pragma unroll
    for (int j=0;j<16;j++) acc[j] = (f32x4){0.f,0.f,0.f,0.f};

#define GSTAGE(T, BUF) do { \
        const short* As_ = x0  + (T)*32; \
        const short* Bs_ = Wto + (T)*32; \
        if (wave < 4) gload_lds16(As_ + srcA, pool + (BUF)*4096 + wave*1024); \
        char* dB_ = pool + 8192 + (BUF)*32768; \
        gload_lds16(Bs_ + srcB[0], dB_ +     0 + wave*1024); \
        gload_lds16(Bs_ + srcB[1], dB_ +  8192 + wave*1024); \
        gload_lds16(Bs_ + srcB[2], dB_ + 16384 + wave*1024); \
        gload_lds16(Bs_ + srcB[3], dB_ + 24576 + wave*1024); \
    } while(0)

    GSTAGE(0, 0);
    __syncthreads();

    int cur = 0;
    for (int t=0; t<16; ++t) {
        if (t < 15) GSTAGE(t+1, cur^1);
        const char* pA = pool + cur*4096;
        const char* pB = pool + 8192 + cur*32768;
        int R = (wave>>1)*16 + fr;
        bf16x8 af = *(const bf16x8*)(pA + R*64 + ((g4 ^ ((R>>1)&3))<<4));
        #pragma unroll
        for (int j=0;j<16;j++) {
            int Rb = (wave&1)*256 + j*16 + fr;
            bf16x8 bf = *(const bf16x8*)(pB + Rb*64 + ((g4 ^ ((Rb>>1)&3))<<4));
            acc[j] = MFMA16(af, bf, acc[j]);
        }
        __syncthreads();
        cur ^= 1;
    }
#undef GSTAGE

    // epilogue 1: relu(acc+bias) -> overlay [64][520] bf16
    short (*Lo)[520] = (short(*)[520])pool;
    {
        int wrow = (wave>>1)*16 + g4*4;
        int cbase = (wave&1)*256;
        #pragma unroll
        for (int j=0;j<16;j++) {
            int col = cbase + j*16 + fr;
            float bb = bo[col];
            #pragma unroll
            for (int r=0;r<4;r++) {
                float vv = acc[j][r] + bb;
                vv = vv > 0.f ? vv : 0.f;
                Lo[wrow + r][col] = f2bf(vv);
            }
        }
    }
    __syncthreads();

    // epilogue 2: per row: x = x0 + relu(...); LN1; write f32 out.
    // 8 waves x 8 rows each; lane covers 8 cols.
    int f0 = lane*8;
    float4 gg0 = *(const float4*)&g[f0],  gg1 = *(const float4*)&g[f0+4];
    float4 tt0 = *(const float4*)&bt[f0], tt1 = *(const float4*)&bt[f0+4];
    #pragma unroll
    for (int rr=0; rr<8; ++rr) {
        int row = wave*8 + rr;
        s16x8 rv = *(s16x8*)&Lo[row][f0];
        s16x8 xv = *(const s16x8*)&x0[(size_t)(m0+row)*DIM + f0];
        float x[8];
        float sm=0.f, sq=0.f;
        #pragma unroll
        for (int j=0;j<8;j++) { x[j] = bf2f(rv[j]) + bf2f(xv[j]); sm += x[j]; sq += x[j]*x[j]; }
        #pragma unroll
        for (int off=1; off<64; off<<=1) { sm += __shfl_xor(sm,off); sq += __shfl_xor(sq,off); }
        float mean = sm*(1.0f/512.0f);
        float var  = sq*(1.0f/512.0f) - mean*mean;
        float inv  = rsqrtf(var + 1e-5f);
        float4 o0, o1;
        o0.x=(x[0]-mean)*inv*gg0.x + tt0.x; o0.y=(x[1]-mean)*inv*gg0.y + tt0.y;
        o0.z=(x[2]-mean)*inv*gg0.z + tt0.z; o0.w=(x[3]-mean)*inv*gg0.w + tt0.w;
        o1.x=(x[4]-mean)*inv*gg1.x + tt1.x; o1.y=(x[5]-mean)*inv*gg1.y + tt1.y;
        o1.z=(x[6]-mean)*inv*gg1.z + tt1.z; o1.w=(x[7]-mean)*inv*gg1.w + tt1.w;
        *(float4*)&out[(size_t)(m0+row)*DIM + f0]     = o0;
        *(float4*)&out[(size_t)(m0+row)*DIM + f0 + 4] = o1;
    }
}

// ---------------------------------------------------------------------------
extern "C" void kernel_launch(void* const* d_in, const int* in_sizes, int n_in,
                              void* d_out, int out_size, void* d_ws, size_t ws_size,
                              hipStream_t stream)
{
    const float* Q  = (const float*)d_in[0];
    const float* K  = (const float*)d_in[1];
    const float* Wq = (const float*)d_in[2];
    const float* bq = (const float*)d_in[3];
    const float* Wk = (const float*)d_in[4];
    const float* bk = (const float*)d_in[5];
    const float* Wv = (const float*)d_in[6];
    const float* bv = (const float*)d_in[7];
    const float* Wo = (const float*)d_in[8];
    const float* bo = (const float*)d_in[9];
    const float* g0 = (const float*)d_in[10];
    const float* be0= (const float*)d_in[11];
    const float* g1 = (const float*)d_in[12];
    const float* be1= (const float*)d_in[13];
    float* out = (float*)d_out;

    char* ws = (char*)d_ws;
    size_t off = 0;
    short* Wt = (short*)(ws + off); off += (size_t)4*DIM*DIM*2;      //  2.10 MB
    short* qb = (short*)(ws + off); off += (size_t)MTOT*DIM*2;       // 16.78 MB
    short* kb = (short*)(ws + off); off += (size_t)MTOT*DIM*2;
    short* vT = (short*)(ws + off); off += (size_t)MTOT*DIM*2;
    short* Oh = (short*)(ws + off); off += (size_t)MTOT*DIM*2;       // total ~69.2 MB
    short* x0 = vT;   // vT dead after k_attn

    k_wprep   <<<dim3(8,8,4),   256, 0, stream>>>(Wq,Wk,Wv,Wo,Wt);
    k_projqkv <<<dim3(128,4,3), 256, 0, stream>>>(Q,K,Wt,bq,bk,bv,qb,kb,vT);
    k_attn    <<<dim3(2,NH,NB), 256, 0, stream>>>(qb,kb,vT,Oh);
    k_ln0     <<<dim3(MTOT/4),  256, 0, stream>>>(qb,Oh,g0,be0,x0);
    k_gemmy_ln<<<dim3(256),     512, 0, stream>>>(x0, Wt + (size_t)3*DIM*DIM, bo, g1, be1, out);
}